// Round 1
// baseline (510.443 us; speedup 1.0000x reference)
//
#include <hip/hip_runtime.h>

// ---------------------------------------------------------------------------
// VQ layer: N=32768 latents, K=8192 prototypes, D=512 (fp32 in/out).
// out[0..N*D) = prototypes[argmin_k ||x_n - p_k||^2];  out[N*D] = 1.25*mean((q-x)^2)
//
// R8 vs R7: break the 2-barrier-per-slice drain (m97-structure ~39% MfmaUtil
// ceiling) with the T3+T4 counted-vmcnt pipeline:
//   - A tile (128x512B) hoisted to registers once (a[4][2] i32x8 = 64 VGPR);
//     was re-staged 8x per block and re-read from LDS every slice.
//   - B: 3 x 16KB LDS buffers, stage step s+2 each step, wait vmcnt(4) (not 0)
//     + raw s_barrier -> prefetch stays in flight ACROSS barriers. One barrier
//     per step instead of two; vmcnt(0) only at the final step.
//   - pnC staged to LDS at prologue: fold reads become ds_read (lgkm), so
//     they cannot pollute the counted vmcnt discipline.
//   - sched_barrier(0) brackets each step body: ds_reads must not be moved
//     across the raw s_barrier by the scheduler (buffer s-1 is overwritten by
//     stage s+2 right after the barrier).
// Same XOR-swizzled 16B-chunk layout (R6: 0 bank conflicts), same MX-scaled
// mfma_scale_f32_16x16x128_f8f6f4 (scale=127 -> x1.0), same k-map.
// Register budget: acc 64 + A 64 + v 8 + addressing/frags ~25 -> ~165, under
// (256,3)'s 168 cap. LDS 52KB -> 3 blocks/CU.
// ---------------------------------------------------------------------------

#define N_ROWS 32768
#define K_PROTO 8192
#define DIM 512              // bytes per row in fp8 == elements
#define BM 128
#define BN 128
#define BKB 128              // K-bytes per LDS tile slice = one K=128 MFMA
#define GROUPS 8
#define TILES 8              // GROUPS * TILES * BN == K_PROTO
#define NSTEP 32             // TILES * (DIM/BKB) B-slice steps
#define BUFB 16384           // bytes per B buffer (BN * BKB)

typedef unsigned char u8;
typedef unsigned int u32;
typedef __attribute__((ext_vector_type(4))) int i32x4;        // 16B LDS chunk
typedef __attribute__((ext_vector_type(8))) int i32x8;        // 32B MFMA A/B frag
typedef __attribute__((ext_vector_type(4))) float f32x4;      // MFMA C/D frag

__device__ __forceinline__ void async16(const void* g, void* s) {
    __builtin_amdgcn_global_load_lds(
        (const __attribute__((address_space(1))) void*)g,
        (__attribute__((address_space(3))) void*)s, 16, 0, 0);
}

// pack 4 floats -> 4 fp8 e4m3 bytes (HW RNE, saturating)
__device__ __forceinline__ int pk4(float a, float b, float c, float d) {
    int v = 0;
    v = __builtin_amdgcn_cvt_pk_fp8_f32(a, b, v, false);   // bytes 0,1
    v = __builtin_amdgcn_cvt_pk_fp8_f32(c, d, v, true);    // bytes 2,3
    return v;
}

// ---------------------------------------------------------------------------
// latents fp32 -> fp8, 16 elems/thread. grid 4096 x 256. blocks 0..127 also
// init best[].
__global__ void __launch_bounds__(256) conv_latents(const float* __restrict__ X,
                                                    u8* __restrict__ Xf,
                                                    u32* __restrict__ best) {
    if (blockIdx.x < 128) best[blockIdx.x * 256 + threadIdx.x] = 0xFFFFFFFFu;
    size_t i = ((size_t)blockIdx.x * 256 + threadIdx.x) * 16;
    float4 a = ((const float4*)(X + i))[0];
    float4 b = ((const float4*)(X + i))[1];
    float4 c = ((const float4*)(X + i))[2];
    float4 d = ((const float4*)(X + i))[3];
    int4 o;
    o.x = pk4(a.x, a.y, a.z, a.w);
    o.y = pk4(b.x, b.y, b.z, b.w);
    o.z = pk4(c.x, c.y, c.z, c.w);
    o.w = pk4(d.x, d.y, d.z, d.w);
    *(int4*)(Xf + i) = o;
}

// protos fp32 -> fp8 (x8192; raw p ~1e-4 would be denormal) + pnC[k] =
// 8192*||p||^2 + 256 (positive scaled scores -> bit-monotone u32 key).
__global__ void __launch_bounds__(256) conv_protos(const float* __restrict__ P,
                                                   u8* __restrict__ Pf,
                                                   float* __restrict__ pnC) {
    int row  = blockIdx.x * 4 + (threadIdx.x >> 6);
    int lane = threadIdx.x & 63;
    const float* src = P + (size_t)row * DIM + lane * 8;
    float4 a = ((const float4*)src)[0];
    float4 b = ((const float4*)src)[1];
    int2 o;
    o.x = pk4(a.x * 8192.0f, a.y * 8192.0f, a.z * 8192.0f, a.w * 8192.0f);
    o.y = pk4(b.x * 8192.0f, b.y * 8192.0f, b.z * 8192.0f, b.w * 8192.0f);
    *(int2*)(Pf + (size_t)row * DIM + lane * 8) = o;
    float ss = a.x*a.x + a.y*a.y + a.z*a.z + a.w*a.w
             + b.x*b.x + b.y*b.y + b.z*b.z + b.w*b.w;
    #pragma unroll
    for (int off = 32; off; off >>= 1) ss += __shfl_down(ss, off);
    if (lane == 0) pnC[row] = ss * 8192.0f + 256.0f;
}

// ---------------------------------------------------------------------------
// stage B-slice for step s2 into buffer (s2 % 3). 4 async16 per thread.
__device__ __forceinline__ void stage_b(const u8* __restrict__ Pf, u8* BsF,
                                        int s2, int colg, const int (&voff)[4],
                                        int tid) {
    const int t2 = s2 >> 2, kt2 = s2 & 3, sb = s2 % 3;
    const u8* src = Pf + (size_t)(colg + t2 * BN) * DIM + kt2 * BKB;
    u8* dst = BsF + sb * BUFB + tid * 16;
    #pragma unroll
    for (int i = 0; i < 4; i++)
        async16(src + voff[i], dst + i * 4096);
}

// ---------------------------------------------------------------------------
// Score: block = 128 rows x (TILES=8 x 128) cols; wave w owns rows
// [w*32, w*32+32) x 128 cols. A in registers; B through a 3-deep pipelined
// LDS buffer with counted vmcnt.
// ---------------------------------------------------------------------------
__global__ void __launch_bounds__(256, 3) vq_score_kernel(const u8* __restrict__ Xf,
                                                          const u8* __restrict__ Pf,
                                                          const float* __restrict__ pnC,
                                                          u32* __restrict__ best) {
    __shared__ __align__(16) u8 lds_raw[3 * BUFB + 4096];   // 52 KB
    u8* BsF = lds_raw;
    const float* pcs = (const float*)(lds_raw + 3 * BUFB);

    const int tid  = threadIdx.x;
    const int row0 = blockIdx.x * BM;
    const int colg = blockIdx.y * (TILES * BN);

    const int w    = tid >> 6, lane = tid & 63;
    const int quad = lane >> 4, l15 = lane & 15;

    // per-thread staging constants: thread handles 16B chunks f = tid + i*256
    // of a [128 rows][8 chunks] slice; global chunk c = (f&7) ^ (row&7) so the
    // LINEAR LDS position (f&7) holds the swizzled chunk (pre-swizzled-source
    // pattern; global_load_lds dest must be linear).
    int voff[4];
    #pragma unroll
    for (int i = 0; i < 4; i++) {
        int f = tid + i * 256;
        int row = f >> 3, c = (f & 7) ^ (row & 7);
        voff[i] = row * DIM + c * 16;
    }

    // k-map: lane quad q consumes global chunks q (frag bytes 0..15) and q|4
    // (bytes 16..31) of its row; pos = (q ^ (row&7))*16; row&7 == l15&7 for
    // all rows we touch (offsets are multiples of 16).
    const int x7   = l15 & 7;
    const int pos0 = (quad ^ x7) << 4;
    const int pos1 = pos0 ^ 64;

    // ---- prologue 1: A tile -> registers (2 passes of 2 slices through
    // buffers 0+1), pnC column slice -> LDS.
    i32x8 a[4][2];
    #pragma unroll
    for (int r = 0; r < 2; r++) {
        #pragma unroll
        for (int i = 0; i < 8; i++) {
            int f = tid + i * 256;           // 0..2047 over two 16KB slices
            int sl = f >> 10;                // which slice of this pass
            int fi = f & 1023;
            int row = fi >> 3, c = (fi & 7) ^ (row & 7);
            async16(Xf + (size_t)(row0 + row) * DIM + (2 * r + sl) * BKB + c * 16,
                    BsF + f * 16);
        }
        if (r == 0)  // 4KB of pnC for this column group (1024 floats)
            async16((const u8*)(pnC + colg) + tid * 16, lds_raw + 3 * BUFB + tid * 16);
        __syncthreads();                     // full drain: stages + prior reads
        #pragma unroll
        for (int sl = 0; sl < 2; sl++) {
            const u8* Ar = BsF + sl * BUFB + (w * 32 + l15) * BKB;
            #pragma unroll
            for (int tm = 0; tm < 2; tm++) {
                const u8* p = Ar + tm * 16 * BKB;
                a[2 * r + sl][tm] = __builtin_shufflevector(
                    *(const i32x4*)(p + pos0), *(const i32x4*)(p + pos1),
                    0, 1, 2, 3, 4, 5, 6, 7);
            }
        }
        __syncthreads();                     // reads done before buffers reused
    }

    // ---- prologue 2: stage B steps 0,1 -> buffers 0,1 (8 loads in flight)
    stage_b(Pf, BsF, 0, colg, voff, tid);
    stage_b(Pf, BsF, 1, colg, voff, tid);

    u32 v[2][4];
    #pragma unroll
    for (int i = 0; i < 2; i++)
        #pragma unroll
        for (int r = 0; r < 4; r++) v[i][r] = 0xFFFFFFFFu;

    // ---- main loop: 8 tiles x 4 slices = 32 steps, one barrier per step.
    // Steady state: wait vmcnt(4) retires exactly stage s (stage s+1 stays in
    // flight); after the barrier, buffer (s+2)%3 == (s-1)%3 is dead (all waves
    // consumed it before entering this barrier) -> stage s+2 into it.
    for (int t = 0; t < TILES; ++t) {
        f32x4 acc[2][8];
        #pragma unroll
        for (int i = 0; i < 2; i++)
            #pragma unroll
            for (int j = 0; j < 8; j++) acc[i][j] = (f32x4)0.0f;

        #pragma unroll
        for (int kt = 0; kt < 4; ++kt) {
            const int s = t * 4 + kt;
            if (kt == 3 && t == TILES - 1)
                asm volatile("s_waitcnt vmcnt(0)" ::: "memory");
            else
                asm volatile("s_waitcnt vmcnt(4)" ::: "memory");
            __builtin_amdgcn_s_barrier();
            __builtin_amdgcn_sched_barrier(0);   // no ds_read above this point

            if (s + 2 < NSTEP) stage_b(Pf, BsF, s + 2, colg, voff, tid);

            const u8* Brow = BsF + (s % 3) * BUFB + l15 * BKB;
            #pragma unroll
            for (int tn = 0; tn < 8; tn++) {
                const u8* bp = Brow + tn * 16 * BKB;
                i32x8 b = __builtin_shufflevector(
                    *(const i32x4*)(bp + pos0), *(const i32x4*)(bp + pos1),
                    0, 1, 2, 3, 4, 5, 6, 7);
                // fmtA=0 (fp8 e4m3), fmtB=0, scales 127 -> 2^0
                acc[0][tn] = __builtin_amdgcn_mfma_scale_f32_16x16x128_f8f6f4(
                    a[kt][0], b, acc[0][tn], 0, 0, 0, 127, 0, 127);
                acc[1][tn] = __builtin_amdgcn_mfma_scale_f32_16x16x128_f8f6f4(
                    a[kt][1], b, acc[1][tn], 0, 0, 0, 127, 0, 127);
            }
            __builtin_amdgcn_sched_barrier(0);   // no ds_read below next barrier
        }

        // fold tile into register argmin; pc from LDS (ds_read: must not touch
        // vmcnt). C/D layout: col = l15, row = quad*4 + r (+tm*16+w*32).
        #pragma unroll
        for (int tn = 0; tn < 8; tn++) {
            const int ci = t * BN + tn * 16 + l15;
            const float pc = pcs[ci];
            const u32 kidx = (u32)(colg + ci);
            #pragma unroll
            for (int tm = 0; tm < 2; tm++)
                #pragma unroll
                for (int r = 0; r < 4; r++) {
                    float sk = fmaf(-2.0f, acc[tm][tn][r], pc);
                    u32 key = (__float_as_uint(sk) & 0xFFFFE000u) | kidx;
                    if (key < v[tm][r]) v[tm][r] = key;
                }
        }
    }

    // quad-local xor-reduce over the 16 cols held across l15; one writer lane
    // per row -> direct global atomicMin.
    #pragma unroll
    for (int tm = 0; tm < 2; tm++)
        #pragma unroll
        for (int r = 0; r < 4; r++) {
            u32 x = v[tm][r];
            #pragma unroll
            for (int off = 1; off < 16; off <<= 1) {
                u32 o = (u32)__shfl_xor((int)x, off);
                if (o < x) x = o;
            }
            if (l15 == 0)
                atomicMin(&best[row0 + w * 32 + tm * 16 + quad * 4 + r], x);
        }
}

// ---------------------------------------------------------------------------
// Gather chosen prototype (original fp32) + per-row loss partial (NO atomics).
__global__ void __launch_bounds__(128) vq_gather_kernel(const float* __restrict__ X,
                                                        const float* __restrict__ P,
                                                        const u32* __restrict__ best,
                                                        float* __restrict__ out,
                                                        float* __restrict__ partial) {
    const int n = blockIdx.x, t = threadIdx.x;
    const u32 k = best[n] & (K_PROTO - 1);
    const float4 p = ((const float4*)(P + (size_t)k * DIM))[t];
    const float4 x = ((const float4*)(X + (size_t)n * DIM))[t];
    ((float4*)(out + (size_t)n * DIM))[t] = p;
    float dx = p.x - x.x, dy = p.y - x.y, dz = p.z - x.z, dw = p.w - x.w;
    float ss = dx * dx + dy * dy + dz * dz + dw * dw;
    #pragma unroll
    for (int off = 32; off; off >>= 1) ss += __shfl_down(ss, off);
    __shared__ float part[2];
    if ((t & 63) == 0) part[t >> 6] = ss;
    __syncthreads();
    if (t == 0) partial[n] = part[0] + part[1];
}

// single-block final loss reduction: 32768 partials -> out[N*D].
__global__ void __launch_bounds__(256) loss_reduce(const float* __restrict__ partial,
                                                   float* __restrict__ out) {
    const int t = threadIdx.x;
    float s = 0.0f;
    #pragma unroll
    for (int i = 0; i < 32; i++) {            // 256 thr x 32 float4 = 32768
        float4 a = ((const float4*)partial)[t * 32 + i];
        s += a.x + a.y + a.z + a.w;
    }
    #pragma unroll
    for (int off = 32; off; off >>= 1) s += __shfl_down(s, off);
    __shared__ float part[4];
    if ((t & 63) == 0) part[t >> 6] = s;
    __syncthreads();
    if (t == 0)
        out[(size_t)N_ROWS * DIM] =
            (part[0] + part[1] + part[2] + part[3]) * 7.450580596923828e-08f; // 1.25/(N*D)
}

// ---------------------------------------------------------------------------
extern "C" void kernel_launch(void* const* d_in, const int* in_sizes, int n_in,
                              void* d_out, int out_size, void* d_ws, size_t ws_size,
                              hipStream_t stream) {
    const float* X = (const float*)d_in[0];   // latents  [32768,512] fp32
    const float* P = (const float*)d_in[1];   // protos   [8192,512]  fp32
    float* out = (float*)d_out;
    char* ws = (char*)d_ws;

    // ws: Xf 16MB | Pf 4MB | pnC 32KB | best(u32) 128KB | partial 128KB
    u8* Xf = (u8*)ws;
    u8* Pf = (u8*)(ws + 16777216);
    float* pnC = (float*)(ws + 20971520);
    u32* best = (u32*)(ws + 21004288);
    float* partial = (float*)(ws + 21135360);

    conv_latents<<<dim3(4096), dim3(256), 0, stream>>>(X, Xf, best);
    conv_protos<<<dim3(2048), dim3(256), 0, stream>>>(P, Pf, pnC);
    vq_score_kernel<<<dim3(N_ROWS / BM, GROUPS), dim3(256), 0, stream>>>(Xf, Pf, pnC, best);
    vq_gather_kernel<<<dim3(N_ROWS), dim3(128), 0, stream>>>(X, P, best, out, partial);
    loss_reduce<<<dim3(1), dim3(256), 0, stream>>>(partial, out);
}

// Round 2
// 312.943 us; speedup vs baseline: 1.6311x; 1.6311x over previous
//
#include <hip/hip_runtime.h>

// ---------------------------------------------------------------------------
// VQ layer: N=32768 latents, K=8192 prototypes, D=512 (fp32 in/out).
// out[0..N*D) = prototypes[argmin_k ||x_n - p_k||^2];  out[N*D] = 1.25*mean((q-x)^2)
//
// R9 vs R8: R8's counted-vmcnt pipeline was correct but __launch_bounds__(256,3)
// capped VGPRs at 168 < demand (~190: acc 64 + A-regs 64 + temps) -> compiler
// spilled a[4][2] to scratch (WRITE_SIZE 8.5->542 MB, MfmaUtil 14%). Fix:
// (256,2) -> cap 256, 2 blocks/CU (2 waves/SIMD, the HK GEMM operating point;
// counted-vmcnt pipelining supplies ILP so low TLP is fine). Also add T5
// s_setprio(1) around the MFMA cluster: the 2 co-resident blocks are not
// barrier-synced with each other -> phase-diverse waves per SIMD (the regime
// where setprio measured +21-39%).
//
// Structure (unchanged from R8):
//   - A tile (128x512B) hoisted to registers once (a[4][2] i32x8 = 64 VGPR).
//   - B: 3 x 16KB LDS buffers, stage step s+2 each step, wait vmcnt(4) (not 0)
//     + raw s_barrier -> prefetch stays in flight ACROSS barriers. One barrier
//     per step; vmcnt(0) only at the final step.
//   - pnC staged to LDS at prologue (fold reads are lgkm, never touch vmcnt).
//   - sched_barrier(0) brackets each step body (ds_reads must not cross the
//     raw barriers; buffer s-1 is overwritten by stage s+2 after the barrier).
// Same XOR-swizzled 16B-chunk layout (0 bank conflicts), same MX-scaled
// mfma_scale_f32_16x16x128_f8f6f4 (scale=127 -> x1.0), same k-map.
// Per-CU step ceiling: MFMA 64x8.6=550cy vs LDS 64xb128x12=768cy -> ~72% cap.
// ---------------------------------------------------------------------------

#define N_ROWS 32768
#define K_PROTO 8192
#define DIM 512              // bytes per row in fp8 == elements
#define BM 128
#define BN 128
#define BKB 128              // K-bytes per LDS tile slice = one K=128 MFMA
#define GROUPS 8
#define TILES 8              // GROUPS * TILES * BN == K_PROTO
#define NSTEP 32             // TILES * (DIM/BKB) B-slice steps
#define BUFB 16384           // bytes per B buffer (BN * BKB)

typedef unsigned char u8;
typedef unsigned int u32;
typedef __attribute__((ext_vector_type(4))) int i32x4;        // 16B LDS chunk
typedef __attribute__((ext_vector_type(8))) int i32x8;        // 32B MFMA A/B frag
typedef __attribute__((ext_vector_type(4))) float f32x4;      // MFMA C/D frag

__device__ __forceinline__ void async16(const void* g, void* s) {
    __builtin_amdgcn_global_load_lds(
        (const __attribute__((address_space(1))) void*)g,
        (__attribute__((address_space(3))) void*)s, 16, 0, 0);
}

// pack 4 floats -> 4 fp8 e4m3 bytes (HW RNE, saturating)
__device__ __forceinline__ int pk4(float a, float b, float c, float d) {
    int v = 0;
    v = __builtin_amdgcn_cvt_pk_fp8_f32(a, b, v, false);   // bytes 0,1
    v = __builtin_amdgcn_cvt_pk_fp8_f32(c, d, v, true);    // bytes 2,3
    return v;
}

// ---------------------------------------------------------------------------
// latents fp32 -> fp8, 16 elems/thread. grid 4096 x 256. blocks 0..127 also
// init best[].
__global__ void __launch_bounds__(256) conv_latents(const float* __restrict__ X,
                                                    u8* __restrict__ Xf,
                                                    u32* __restrict__ best) {
    if (blockIdx.x < 128) best[blockIdx.x * 256 + threadIdx.x] = 0xFFFFFFFFu;
    size_t i = ((size_t)blockIdx.x * 256 + threadIdx.x) * 16;
    float4 a = ((const float4*)(X + i))[0];
    float4 b = ((const float4*)(X + i))[1];
    float4 c = ((const float4*)(X + i))[2];
    float4 d = ((const float4*)(X + i))[3];
    int4 o;
    o.x = pk4(a.x, a.y, a.z, a.w);
    o.y = pk4(b.x, b.y, b.z, b.w);
    o.z = pk4(c.x, c.y, c.z, c.w);
    o.w = pk4(d.x, d.y, d.z, d.w);
    *(int4*)(Xf + i) = o;
}

// protos fp32 -> fp8 (x8192; raw p ~1e-4 would be denormal) + pnC[k] =
// 8192*||p||^2 + 256 (positive scaled scores -> bit-monotone u32 key).
__global__ void __launch_bounds__(256) conv_protos(const float* __restrict__ P,
                                                   u8* __restrict__ Pf,
                                                   float* __restrict__ pnC) {
    int row  = blockIdx.x * 4 + (threadIdx.x >> 6);
    int lane = threadIdx.x & 63;
    const float* src = P + (size_t)row * DIM + lane * 8;
    float4 a = ((const float4*)src)[0];
    float4 b = ((const float4*)src)[1];
    int2 o;
    o.x = pk4(a.x * 8192.0f, a.y * 8192.0f, a.z * 8192.0f, a.w * 8192.0f);
    o.y = pk4(b.x * 8192.0f, b.y * 8192.0f, b.z * 8192.0f, b.w * 8192.0f);
    *(int2*)(Pf + (size_t)row * DIM + lane * 8) = o;
    float ss = a.x*a.x + a.y*a.y + a.z*a.z + a.w*a.w
             + b.x*b.x + b.y*b.y + b.z*b.z + b.w*b.w;
    #pragma unroll
    for (int off = 32; off; off >>= 1) ss += __shfl_down(ss, off);
    if (lane == 0) pnC[row] = ss * 8192.0f + 256.0f;
}

// ---------------------------------------------------------------------------
// stage B-slice for step s2 into buffer (s2 % 3). 4 async16 per thread.
__device__ __forceinline__ void stage_b(const u8* __restrict__ Pf, u8* BsF,
                                        int s2, int colg, const int (&voff)[4],
                                        int tid) {
    const int t2 = s2 >> 2, kt2 = s2 & 3, sb = s2 % 3;
    const u8* src = Pf + (size_t)(colg + t2 * BN) * DIM + kt2 * BKB;
    u8* dst = BsF + sb * BUFB + tid * 16;
    #pragma unroll
    for (int i = 0; i < 4; i++)
        async16(src + voff[i], dst + i * 4096);
}

// ---------------------------------------------------------------------------
// Score: block = 128 rows x (TILES=8 x 128) cols; wave w owns rows
// [w*32, w*32+32) x 128 cols. A in registers; B through a 3-deep pipelined
// LDS buffer with counted vmcnt.
// ---------------------------------------------------------------------------
__global__ void __launch_bounds__(256, 2) vq_score_kernel(const u8* __restrict__ Xf,
                                                          const u8* __restrict__ Pf,
                                                          const float* __restrict__ pnC,
                                                          u32* __restrict__ best) {
    __shared__ __align__(16) u8 lds_raw[3 * BUFB + 4096];   // 52 KB
    u8* BsF = lds_raw;
    const float* pcs = (const float*)(lds_raw + 3 * BUFB);

    const int tid  = threadIdx.x;
    const int row0 = blockIdx.x * BM;
    const int colg = blockIdx.y * (TILES * BN);

    const int w    = tid >> 6, lane = tid & 63;
    const int quad = lane >> 4, l15 = lane & 15;

    // per-thread staging constants: thread handles 16B chunks f = tid + i*256
    // of a [128 rows][8 chunks] slice; global chunk c = (f&7) ^ (row&7) so the
    // LINEAR LDS position (f&7) holds the swizzled chunk (pre-swizzled-source
    // pattern; global_load_lds dest must be linear).
    int voff[4];
    #pragma unroll
    for (int i = 0; i < 4; i++) {
        int f = tid + i * 256;
        int row = f >> 3, c = (f & 7) ^ (row & 7);
        voff[i] = row * DIM + c * 16;
    }

    // k-map: lane quad q consumes global chunks q (frag bytes 0..15) and q|4
    // (bytes 16..31) of its row; pos = (q ^ (row&7))*16; row&7 == l15&7 for
    // all rows we touch (offsets are multiples of 16).
    const int x7   = l15 & 7;
    const int pos0 = (quad ^ x7) << 4;
    const int pos1 = pos0 ^ 64;

    // ---- prologue 1: A tile -> registers (2 passes of 2 slices through
    // buffers 0+1), pnC column slice -> LDS.
    i32x8 a[4][2];
    #pragma unroll
    for (int r = 0; r < 2; r++) {
        #pragma unroll
        for (int i = 0; i < 8; i++) {
            int f = tid + i * 256;           // 0..2047 over two 16KB slices
            int sl = f >> 10;                // which slice of this pass
            int fi = f & 1023;
            int row = fi >> 3, c = (fi & 7) ^ (row & 7);
            async16(Xf + (size_t)(row0 + row) * DIM + (2 * r + sl) * BKB + c * 16,
                    BsF + f * 16);
        }
        if (r == 0)  // 4KB of pnC for this column group (1024 floats)
            async16((const u8*)(pnC + colg) + tid * 16, lds_raw + 3 * BUFB + tid * 16);
        __syncthreads();                     // full drain: stages + prior reads
        #pragma unroll
        for (int sl = 0; sl < 2; sl++) {
            const u8* Ar = BsF + sl * BUFB + (w * 32 + l15) * BKB;
            #pragma unroll
            for (int tm = 0; tm < 2; tm++) {
                const u8* p = Ar + tm * 16 * BKB;
                a[2 * r + sl][tm] = __builtin_shufflevector(
                    *(const i32x4*)(p + pos0), *(const i32x4*)(p + pos1),
                    0, 1, 2, 3, 4, 5, 6, 7);
            }
        }
        __syncthreads();                     // reads done before buffers reused
    }

    // ---- prologue 2: stage B steps 0,1 -> buffers 0,1 (8 loads in flight)
    stage_b(Pf, BsF, 0, colg, voff, tid);
    stage_b(Pf, BsF, 1, colg, voff, tid);

    u32 v[2][4];
    #pragma unroll
    for (int i = 0; i < 2; i++)
        #pragma unroll
        for (int r = 0; r < 4; r++) v[i][r] = 0xFFFFFFFFu;

    // ---- main loop: 8 tiles x 4 slices = 32 steps, one barrier per step.
    // Steady state: wait vmcnt(4) retires exactly stage s (stage s+1 stays in
    // flight); after the barrier, buffer (s+2)%3 == (s-1)%3 is dead (all waves
    // consumed it before entering this barrier) -> stage s+2 into it.
    for (int t = 0; t < TILES; ++t) {
        f32x4 acc[2][8];
        #pragma unroll
        for (int i = 0; i < 2; i++)
            #pragma unroll
            for (int j = 0; j < 8; j++) acc[i][j] = (f32x4)0.0f;

        #pragma unroll
        for (int kt = 0; kt < 4; ++kt) {
            const int s = t * 4 + kt;
            if (kt == 3 && t == TILES - 1)
                asm volatile("s_waitcnt vmcnt(0)" ::: "memory");
            else
                asm volatile("s_waitcnt vmcnt(4)" ::: "memory");
            __builtin_amdgcn_s_barrier();
            __builtin_amdgcn_sched_barrier(0);   // no ds_read above this point

            if (s + 2 < NSTEP) stage_b(Pf, BsF, s + 2, colg, voff, tid);

            const u8* Brow = BsF + (s % 3) * BUFB + l15 * BKB;
            __builtin_amdgcn_s_setprio(1);
            #pragma unroll
            for (int tn = 0; tn < 8; tn++) {
                const u8* bp = Brow + tn * 16 * BKB;
                i32x8 b = __builtin_shufflevector(
                    *(const i32x4*)(bp + pos0), *(const i32x4*)(bp + pos1),
                    0, 1, 2, 3, 4, 5, 6, 7);
                // fmtA=0 (fp8 e4m3), fmtB=0, scales 127 -> 2^0
                acc[0][tn] = __builtin_amdgcn_mfma_scale_f32_16x16x128_f8f6f4(
                    a[kt][0], b, acc[0][tn], 0, 0, 0, 127, 0, 127);
                acc[1][tn] = __builtin_amdgcn_mfma_scale_f32_16x16x128_f8f6f4(
                    a[kt][1], b, acc[1][tn], 0, 0, 0, 127, 0, 127);
            }
            __builtin_amdgcn_s_setprio(0);
            __builtin_amdgcn_sched_barrier(0);   // no ds_read below next barrier
        }

        // fold tile into register argmin; pc from LDS (ds_read: must not touch
        // vmcnt). C/D layout: col = l15, row = quad*4 + r (+tm*16+w*32).
        #pragma unroll
        for (int tn = 0; tn < 8; tn++) {
            const int ci = t * BN + tn * 16 + l15;
            const float pc = pcs[ci];
            const u32 kidx = (u32)(colg + ci);
            #pragma unroll
            for (int tm = 0; tm < 2; tm++)
                #pragma unroll
                for (int r = 0; r < 4; r++) {
                    float sk = fmaf(-2.0f, acc[tm][tn][r], pc);
                    u32 key = (__float_as_uint(sk) & 0xFFFFE000u) | kidx;
                    if (key < v[tm][r]) v[tm][r] = key;
                }
        }
    }

    // quad-local xor-reduce over the 16 cols held across l15; one writer lane
    // per row -> direct global atomicMin.
    #pragma unroll
    for (int tm = 0; tm < 2; tm++)
        #pragma unroll
        for (int r = 0; r < 4; r++) {
            u32 x = v[tm][r];
            #pragma unroll
            for (int off = 1; off < 16; off <<= 1) {
                u32 o = (u32)__shfl_xor((int)x, off);
                if (o < x) x = o;
            }
            if (l15 == 0)
                atomicMin(&best[row0 + w * 32 + tm * 16 + quad * 4 + r], x);
        }
}

// ---------------------------------------------------------------------------
// Gather chosen prototype (original fp32) + per-row loss partial (NO atomics).
__global__ void __launch_bounds__(128) vq_gather_kernel(const float* __restrict__ X,
                                                        const float* __restrict__ P,
                                                        const u32* __restrict__ best,
                                                        float* __restrict__ out,
                                                        float* __restrict__ partial) {
    const int n = blockIdx.x, t = threadIdx.x;
    const u32 k = best[n] & (K_PROTO - 1);
    const float4 p = ((const float4*)(P + (size_t)k * DIM))[t];
    const float4 x = ((const float4*)(X + (size_t)n * DIM))[t];
    ((float4*)(out + (size_t)n * DIM))[t] = p;
    float dx = p.x - x.x, dy = p.y - x.y, dz = p.z - x.z, dw = p.w - x.w;
    float ss = dx * dx + dy * dy + dz * dz + dw * dw;
    #pragma unroll
    for (int off = 32; off; off >>= 1) ss += __shfl_down(ss, off);
    __shared__ float part[2];
    if ((t & 63) == 0) part[t >> 6] = ss;
    __syncthreads();
    if (t == 0) partial[n] = part[0] + part[1];
}

// single-block final loss reduction: 32768 partials -> out[N*D].
__global__ void __launch_bounds__(256) loss_reduce(const float* __restrict__ partial,
                                                   float* __restrict__ out) {
    const int t = threadIdx.x;
    float s = 0.0f;
    #pragma unroll
    for (int i = 0; i < 32; i++) {            // 256 thr x 32 float4 = 32768
        float4 a = ((const float4*)partial)[t * 32 + i];
        s += a.x + a.y + a.z + a.w;
    }
    #pragma unroll
    for (int off = 32; off; off >>= 1) s += __shfl_down(s, off);
    __shared__ float part[4];
    if ((t & 63) == 0) part[t >> 6] = s;
    __syncthreads();
    if (t == 0)
        out[(size_t)N_ROWS * DIM] =
            (part[0] + part[1] + part[2] + part[3]) * 7.450580596923828e-08f; // 1.25/(N*D)
}

// ---------------------------------------------------------------------------
extern "C" void kernel_launch(void* const* d_in, const int* in_sizes, int n_in,
                              void* d_out, int out_size, void* d_ws, size_t ws_size,
                              hipStream_t stream) {
    const float* X = (const float*)d_in[0];   // latents  [32768,512] fp32
    const float* P = (const float*)d_in[1];   // protos   [8192,512]  fp32
    float* out = (float*)d_out;
    char* ws = (char*)d_ws;

    // ws: Xf 16MB | Pf 4MB | pnC 32KB | best(u32) 128KB | partial 128KB
    u8* Xf = (u8*)ws;
    u8* Pf = (u8*)(ws + 16777216);
    float* pnC = (float*)(ws + 20971520);
    u32* best = (u32*)(ws + 21004288);
    float* partial = (float*)(ws + 21135360);

    conv_latents<<<dim3(4096), dim3(256), 0, stream>>>(X, Xf, best);
    conv_protos<<<dim3(2048), dim3(256), 0, stream>>>(P, Pf, pnC);
    vq_score_kernel<<<dim3(N_ROWS / BM, GROUPS), dim3(256), 0, stream>>>(Xf, Pf, pnC, best);
    vq_gather_kernel<<<dim3(N_ROWS), dim3(128), 0, stream>>>(X, P, best, out, partial);
    loss_reduce<<<dim3(1), dim3(256), 0, stream>>>(partial, out);
}